// Round 18
// baseline (226.734 us; speedup 1.0000x reference)
//
#include <hip/hip_runtime.h>

#define NEG_SLOPE 0.2f
static constexpr int BLK = 256;
static constexpr int EPB = 4096;   // edges per bucket-pass block
static constexpr int CAP = 6144;   // per-bucket capacity (mean 4336, +27 sigma)

typedef short bf16x8 __attribute__((ext_vector_type(8)));
typedef float f32x4  __attribute__((ext_vector_type(4)));
typedef unsigned short u16x8 __attribute__((ext_vector_type(8)));
typedef unsigned short u16x4 __attribute__((ext_vector_type(4)));

static inline int cdiv(long a, long b){ return (int)((a + b - 1) / b); }

__device__ __forceinline__ unsigned short f2bf(float f){
    unsigned u = __float_as_uint(f);
    u += 0x7fff + ((u >> 16) & 1);          // RNE
    return (unsigned short)(u >> 16);
}
__device__ __forceinline__ float bf2f(unsigned short h){
    return __uint_as_float(((unsigned)h) << 16);
}
__device__ __forceinline__ float lrelu(float v){
    return v > 0.f ? v : NEG_SLOPE * v;
}

// ---------------- per-graph pointer bundle ----------------
struct GP {
    const int* src; const int* dst; const float* X;
    int* gcnt; int* gbase; int* ebuf; int* rowptr; int* csrsrc;
    unsigned short* h1b; unsigned short* h2b;
    float *as1, *ad1, *as2, *ad2; float* outp;
};

// ---------------- LDS-staged MFMA GEMM: h = W_split x bf16(x) ----------------
// Block = 8 row-tiles (128 rows) x one col-chunk; each wave owns TWO row-tiles.
template<int CO, int CT, bool RELU_IN, bool BF16OUT>
__device__ __forceinline__ void gemm_dev(
    int bid, const float* __restrict__ X,
    const unsigned short* __restrict__ Wt_hi, const unsigned short* __restrict__ Wt_lo,
    const float* __restrict__ avs, const float* __restrict__ avd,
    void* __restrict__ Hout, float* __restrict__ as_out, float* __restrict__ ad_out,
    int N, unsigned short* smem)
{
    constexpr int CHUNKS = CO / (CT * 16);
    constexpr int HWB = CT * 4096;
    int ch, rtb;
    if (CHUNKS == 1){ ch = 0; rtb = bid; } else { ch = bid & 1; rtb = bid >> 1; }
    int c0 = ch * (CT * 16);

    {
        const char* srch = (const char*)(Wt_hi + (size_t)c0 * 128);
        const char* srcl = (const char*)(Wt_lo + (size_t)c0 * 128);
        #pragma unroll
        for (int it = 0; it < CT * 2; ++it){
            int o = (it * 256 + (int)threadIdx.x) * 16;
            const char* sp = (o < HWB) ? (srch + o) : (srcl + (o - HWB));
            u16x8 v = *(const u16x8*)sp;
            int so = o ^ (((o >> 8) & 7) << 4);
            *(u16x8*)((char*)smem + so) = v;
        }
    }
    __syncthreads();

    int wave = threadIdx.x >> 6;
    int lane = threadIdx.x & 63;
    int RTt = N >> 4;
    int rt0 = rtb * 8 + wave;
    int rt1 = rt0 + 4;
    if (rt0 >= RTt) return;
    bool vB = rt1 < RTt;
    int rl = lane & 15, g = lane >> 4;
    const float* xrowA = X + (long)(rt0 * 16 + rl) * 128 + g * 8;
    const float* xrowB = X + (long)((vB ? rt1 : rt0) * 16 + rl) * 128 + g * 8;

    f32x4 accA[CT], accB[CT];
    #pragma unroll
    for (int t = 0; t < CT; t++){ accA[t] = (f32x4)(0.f); accB[t] = (f32x4)(0.f); }

    int sw = (rl & 7) << 4;
    #pragma unroll
    for (int ks = 0; ks < 4; ks++){
        float4 xaA = *(const float4*)(xrowA + ks * 32);
        float4 xbA = *(const float4*)(xrowA + ks * 32 + 4);
        float4 xaB = *(const float4*)(xrowB + ks * 32);
        float4 xbB = *(const float4*)(xrowB + ks * 32 + 4);
        float xvA[8] = {xaA.x, xaA.y, xaA.z, xaA.w, xbA.x, xbA.y, xbA.z, xbA.w};
        float xvB[8] = {xaB.x, xaB.y, xaB.z, xaB.w, xbB.x, xbB.y, xbB.z, xbB.w};
        bf16x8 xbfA, xbfB;
        #pragma unroll
        for (int j = 0; j < 8; j++){
            float xA = xvA[j], xB = xvB[j];
            if (RELU_IN){ xA = fmaxf(xA, 0.f); xB = fmaxf(xB, 0.f); }
            xbfA[j] = (short)f2bf(xA);
            xbfB[j] = (short)f2bf(xB);
        }
        int rbase = rl * 256 + ks * 64 + g * 16;
        #pragma unroll
        for (int t = 0; t < CT; t++){
            bf16x8 wh = *(const bf16x8*)((char*)smem + ((t * 4096 + rbase) ^ sw));
            bf16x8 wl = *(const bf16x8*)((char*)smem + ((HWB + t * 4096 + rbase) ^ sw));
            accA[t] = __builtin_amdgcn_mfma_f32_16x16x32_bf16(wh, xbfA, accA[t], 0, 0, 0);
            accB[t] = __builtin_amdgcn_mfma_f32_16x16x32_bf16(wh, xbfB, accB[t], 0, 0, 0);
            accA[t] = __builtin_amdgcn_mfma_f32_16x16x32_bf16(wl, xbfA, accA[t], 0, 0, 0);
            accB[t] = __builtin_amdgcn_mfma_f32_16x16x32_bf16(wl, xbfB, accB[t], 0, 0, 0);
        }
    }

    #pragma unroll
    for (int half = 0; half < 2; half++){
        if (half == 1 && !vB) break;
        int r0 = (half == 0 ? rt0 : rt1) << 4;
        f32x4* acc = (half == 0) ? accA : accB;
        float ps = 0.f, pd = 0.f;
        #pragma unroll
        for (int t = 0; t < CT; t++){
            int c = c0 + t * 16 + 4 * g;
            float4 vs4 = *(const float4*)(avs + c);
            float4 vd4 = *(const float4*)(avd + c);
            ps += acc[t][0]*vs4.x + acc[t][1]*vs4.y + acc[t][2]*vs4.z + acc[t][3]*vs4.w;
            pd += acc[t][0]*vd4.x + acc[t][1]*vd4.y + acc[t][2]*vd4.z + acc[t][3]*vd4.w;
            long base = (long)(r0 + rl) * CO + c;
            if (BF16OUT){
                u16x4 pk;
                #pragma unroll
                for (int r = 0; r < 4; r++) pk[r] = f2bf(acc[t][r]);
                *(u16x4*)((unsigned short*)Hout + base) = pk;
            } else {
                float4 pv;
                pv.x = acc[t][0]; pv.y = acc[t][1]; pv.z = acc[t][2]; pv.w = acc[t][3];
                *(float4*)((float*)Hout + base) = pv;
            }
        }
        ps += __shfl_xor(ps, 16, 64); ps += __shfl_xor(ps, 32, 64);
        pd += __shfl_xor(pd, 16, 64); pd += __shfl_xor(pd, 32, 64);
        if (g == 0){
            unsafeAtomicAdd(as_out + r0 + rl, ps);
            unsafeAtomicAdd(ad_out + r0 + rl, pd);
        }
    }
}

// ---------------- coarse bucket pass (LDS histogram + reserved scatter) ----------------
__device__ __forceinline__ void bucket_dev(
    int bid, const GP* __restrict__ g, int E, int Etot, int nbk, unsigned short* smem)
{
    int* spk   = (int*)smem;          // 4096 ints
    int* shist = spk + 4096;          // 256
    int* sbase = shist + 256;         // 256
    int tid = (int)threadIdx.x;
    for (int i = tid; i < nbk; i += 256) shist[i] = 0;
    __syncthreads();
    int e0 = bid * EPB;
    #pragma unroll
    for (int i = 0; i < EPB / 256; i++){
        int idx = i * 256 + tid; int e = e0 + idx;
        unsigned p = 0xFFFFFFFFu;
        if (e < Etot){
            int s, d;
            if (e < E){ s = g->src[e]; d = g->dst[e]; } else { s = e - E; d = s; }
            p = ((unsigned)s << 16) | (unsigned)d;
            atomicAdd(&shist[d >> 8], 1);
        }
        spk[idx] = (int)p;
    }
    __syncthreads();
    for (int i = tid; i < nbk; i += 256){
        sbase[i] = atomicAdd(&g->gcnt[i], shist[i]);
        shist[i] = 0;                 // reuse as fill counter
    }
    __syncthreads();
    #pragma unroll
    for (int i = 0; i < EPB / 256; i++){
        int idx = i * 256 + tid;
        unsigned p = (unsigned)spk[idx];
        if (p != 0xFFFFFFFFu){
            int d = (int)(p & 0xFFFFu); int b = d >> 8;
            int r = sbase[b] + atomicAdd(&shist[b], 1);
            if (r < CAP) g->ebuf[(size_t)b * CAP + r] = (int)p;
        }
    }
}

// ---------------- fine pass: per-bucket CSR (rowptr + sorted csrsrc) ----------------
__device__ __forceinline__ void fine_dev(int k, const GP* __restrict__ g, int N, int Etot)
{
    __shared__ int pk2[CAP];
    __shared__ int fs[256];
    __shared__ int fill[256];
    __shared__ int fh[256];
    int tid = (int)threadIdx.x;
    int cnt = min(g->gcnt[k], CAP);
    int bb  = g->gbase[k];
    for (int i = tid; i < cnt; i += 256) pk2[i] = g->ebuf[(size_t)k * CAP + i];
    fh[tid] = 0; fill[tid] = 0;
    __syncthreads();
    for (int i = tid; i < cnt; i += 256) atomicAdd(&fh[pk2[i] & 255], 1);
    __syncthreads();
    int v = fh[tid];
    fs[tid] = v;
    __syncthreads();
    #pragma unroll
    for (int off = 1; off < 256; off <<= 1){
        int t = (tid >= off) ? fs[tid - off] : 0;
        __syncthreads();
        fs[tid] += t;
        __syncthreads();
    }
    int excl = fs[tid] - v;
    __syncthreads();
    fs[tid] = excl;
    __syncthreads();
    int node = k * 256 + tid;
    if (node < N) g->rowptr[node] = bb + excl;
    if (k == 0 && tid == 0) g->rowptr[N] = Etot;
    for (int i = tid; i < cnt; i += 256){
        unsigned p = (unsigned)pk2[i];
        int f = (int)(p & 255u);
        int r = atomicAdd(&fill[f], 1);
        g->csrsrc[bb + fs[f] + r] = (int)(p >> 16);
    }
}

// ---------------- gather core: softmax + weighted row accumulation ----------------
template<int CO, int GRP>
__device__ __forceinline__ void agg_core(
    const int* __restrict__ rowptr, const int* __restrict__ csr_src,
    const float* __restrict__ as, const float* __restrict__ ad,
    const unsigned short* __restrict__ hb, int node, int ql, float* acc)
{
    int start = rowptr[node];
    int deg   = rowptr[node + 1] - start;
    float adv = ad[node];

    int sv[4]; float ev[4];
    #pragma unroll
    for (int q = 0; q < 4; q++){
        int idx = q * GRP + ql;
        sv[q] = 0; ev[q] = -1e30f;
        if (idx < deg){ sv[q] = csr_src[start + idx]; ev[q] = lrelu(as[sv[q]] + adv); }
    }
    float m = fmaxf(fmaxf(ev[0], ev[1]), fmaxf(ev[2], ev[3]));
    if (deg > 4 * GRP){
        for (int j = 4 * GRP + ql; j < deg; j += GRP)
            m = fmaxf(m, lrelu(as[csr_src[start + j]] + adv));
    }
    #pragma unroll
    for (int off = GRP >> 1; off; off >>= 1) m = fmaxf(m, __shfl_xor(m, off, GRP));

    float xq[4]; float sum = 0.f;
    #pragma unroll
    for (int q = 0; q < 4; q++){
        xq[q] = (q * GRP + ql < deg) ? __expf(ev[q] - m) : 0.f;
        sum += xq[q];
    }
    if (deg > 4 * GRP){
        for (int j = 4 * GRP + ql; j < deg; j += GRP)
            sum += __expf(lrelu(as[csr_src[start + j]] + adv) - m);
    }
    #pragma unroll
    for (int off = GRP >> 1; off; off >>= 1) sum += __shfl_xor(sum, off, GRP);
    float inv = 1.f / (sum + 1e-16f);

    #pragma unroll
    for (int i = 0; i < 8; i++) acc[i] = 0.f;

    #pragma unroll
    for (int q = 0; q < 4; q++){
        int rem = deg - q * GRP;
        if (rem <= 0) break;
        int lim = rem < GRP ? rem : GRP;
        float aq = xq[q] * inv; int sq = sv[q];
        int t = 0;
        for (; t + 3 < lim; t += 4){
            int   s0 = __shfl(sq, t+0, GRP), s1 = __shfl(sq, t+1, GRP);
            int   s2 = __shfl(sq, t+2, GRP), s3 = __shfl(sq, t+3, GRP);
            float a0 = __shfl(aq, t+0, GRP), a1 = __shfl(aq, t+1, GRP);
            float a2 = __shfl(aq, t+2, GRP), a3 = __shfl(aq, t+3, GRP);
            u16x8 r0 = *(const u16x8*)(hb + (long)s0 * CO + ql * 8);
            u16x8 r1 = *(const u16x8*)(hb + (long)s1 * CO + ql * 8);
            u16x8 r2 = *(const u16x8*)(hb + (long)s2 * CO + ql * 8);
            u16x8 r3 = *(const u16x8*)(hb + (long)s3 * CO + ql * 8);
            #pragma unroll
            for (int i = 0; i < 8; i++)
                acc[i] += a0 * bf2f(r0[i]) + a1 * bf2f(r1[i])
                        + a2 * bf2f(r2[i]) + a3 * bf2f(r3[i]);
        }
        for (; t < lim; t++){
            int   s0 = __shfl(sq, t, GRP);
            float a0 = __shfl(aq, t, GRP);
            u16x8 r0 = *(const u16x8*)(hb + (long)s0 * CO + ql * 8);
            #pragma unroll
            for (int i = 0; i < 8; i++) acc[i] += a0 * bf2f(r0[i]);
        }
        if (lim < GRP) break;
    }
    if (deg > 4 * GRP){
        for (int j = 4 * GRP; j < deg; j++){
            int sj = csr_src[start + j];               // group-uniform broadcast load
            float aj = __expf(lrelu(as[sj] + adv) - m) * inv;
            u16x8 r0 = *(const u16x8*)(hb + (long)sj * CO + ql * 8);
            #pragma unroll
            for (int i = 0; i < 8; i++) acc[i] += aj * bf2f(r0[i]);
        }
    }
}

// ---------------- agg1: layer-1 agg + fused layer-2 GEMM (16 nodes/block, R15 form) --
__device__ __forceinline__ void agg1_dev(
    int bid, const GP* __restrict__ g, const float* __restrict__ b1,
    const unsigned short* __restrict__ w2h, const unsigned short* __restrict__ w2l,
    const float* __restrict__ avs2, const float* __restrict__ avd2,
    int N, unsigned short* xlds)
{
    int tid = (int)threadIdx.x;
    int grp = tid >> 4, ql = tid & 15;
    int node = bid * 16 + grp;

    {
        u16x8 xv;
        if (node < N){
            float acc[8];
            agg_core<128,16>(g->rowptr, g->csrsrc, g->as1, g->ad1, g->h1b, node, ql, acc);
            #pragma unroll
            for (int i = 0; i < 8; i++)
                xv[i] = f2bf(fmaxf(acc[i] + b1[ql * 8 + i], 0.f));
        } else {
            #pragma unroll
            for (int i = 0; i < 8; i++) xv[i] = 0;
        }
        int bo = (grp * 256 + ql * 16) ^ ((grp & 7) << 4);
        *(u16x8*)((char*)xlds + bo) = xv;
    }
    __syncthreads();

    int lane = tid & 63, wv = tid >> 6;
    int rl = lane & 15, kg = lane >> 4;
    f32x4 d = (f32x4)(0.f);
    #pragma unroll
    for (int kb = 0; kb < 4; kb++){
        bf16x8 af = *(const bf16x8*)((char*)xlds + ((rl * 256 + kb * 64 + kg * 16) ^ ((rl & 7) << 4)));
        long wo = (long)(wv * 16 + rl) * 128 + kb * 32 + kg * 8;
        bf16x8 bh = *(const bf16x8*)(w2h + wo);
        bf16x8 bl = *(const bf16x8*)(w2l + wo);
        d = __builtin_amdgcn_mfma_f32_16x16x32_bf16(af, bh, d, 0, 0, 0);
        d = __builtin_amdgcn_mfma_f32_16x16x32_bf16(af, bl, d, 0, 0, 0);
    }
    // D mapping: lane holds D[row=4*kg+reg][col=rl]; wave covers cols wv*16..+15
    float pvs = avs2[wv * 16 + rl], pvd = avd2[wv * 16 + rl];
    #pragma unroll
    for (int reg = 0; reg < 4; reg++){
        int nd = bid * 16 + 4 * kg + reg;
        float hv = d[reg];
        if (nd < N) g->h2b[(long)nd * 64 + wv * 16 + rl] = f2bf(hv);
        float s_ = hv * pvs, d_ = hv * pvd;
        #pragma unroll
        for (int off = 1; off < 16; off <<= 1){
            s_ += __shfl_xor(s_, off, 16);
            d_ += __shfl_xor(d_, off, 16);
        }
        if (rl == 0 && nd < N){
            unsafeAtomicAdd(g->as2 + nd, s_);
            unsafeAtomicAdd(g->ad2 + nd, d_);
        }
    }
}

// ---------------- agg2: final-layer aggregation (8-lane groups, 32 nodes/block) ------
__device__ __forceinline__ void agg2_dev(
    int bid, const GP* __restrict__ g, const float* __restrict__ bias, int N)
{
    int tid = (int)threadIdx.x;
    int grp = tid >> 3, ql = tid & 7;
    int node = bid * 32 + grp;
    if (node >= N) return;
    float acc[8];
    agg_core<64,8>(g->rowptr, g->csrsrc, g->as2, g->ad2, g->h2b, node, ql, acc);
    float* o = g->outp + (long)node * 64 + ql * 8;
    #pragma unroll
    for (int i = 0; i < 8; i += 4){
        float4 ov;
        ov.x = acc[i+0] + bias[ql * 8 + i + 0];
        ov.y = acc[i+1] + bias[ql * 8 + i + 1];
        ov.z = acc[i+2] + bias[ql * 8 + i + 2];
        ov.w = acc[i+3] + bias[ql * 8 + i + 3];
        *(float4*)(o + i) = ov;
    }
}

// ---------------- kernels ----------------
__global__ __launch_bounds__(BLK) void prep_k(
    const float* __restrict__ W1, const float* __restrict__ W2,
    unsigned short* __restrict__ w1h, unsigned short* __restrict__ w1l,
    unsigned short* __restrict__ w2h, unsigned short* __restrict__ w2l)
{
    int i = blockIdx.x * BLK + threadIdx.x;
    if (i < 128 * 128){
        int c = i >> 7, k = i & 127;
        float w = W1[k * 128 + c];
        unsigned short hi = f2bf(w);
        w1h[i] = hi; w1l[i] = f2bf(w - bf2f(hi));
        if (i < 64 * 128){
            float w2 = W2[k * 64 + c];
            unsigned short hi2 = f2bf(w2);
            w2h[i] = hi2; w2l[i] = f2bf(w2 - bf2f(hi2));
        }
    }
}

// kA: coarse bucket pass (both graphs) + layer-1 GEMM (both graphs)
__global__ __launch_bounds__(256, 4) void kA(
    GP a, GP b, const unsigned short* __restrict__ w1h, const unsigned short* __restrict__ w1l,
    const float* __restrict__ avs1, const float* __restrict__ avd1,
    int EB_a, int EB_b, int GB_a, int GB_b, int E, int Etot, int N, int nbk)
{
    __shared__ unsigned short smem[16384];
    int bid = blockIdx.x;
    if (bid < EB_a){ bucket_dev(bid, &a, E, Etot, nbk, smem); return; }
    bid -= EB_a;
    if (bid < EB_b){ bucket_dev(bid, &b, E, Etot, nbk, smem); return; }
    bid -= EB_b;
    if (bid < GB_a){ gemm_dev<128,4,false,true>(bid, a.X, w1h, w1l, avs1, avd1, a.h1b, a.as1, a.ad1, N, smem); return; }
    bid -= GB_a;
    if (bid < GB_b) gemm_dev<128,4,false,true>(bid, b.X, w1h, w1l, avs1, avd1, b.h1b, b.as1, b.ad1, N, smem);
}

__global__ __launch_bounds__(256) void kscan(GP a, GP b, int nbk){
    const GP* g = (blockIdx.x == 0) ? &a : &b;
    __shared__ int sh[256];
    int tid = (int)threadIdx.x;
    int v = (tid < nbk) ? g->gcnt[tid] : 0;
    sh[tid] = v;
    __syncthreads();
    #pragma unroll
    for (int off = 1; off < 256; off <<= 1){
        int t = (tid >= off) ? sh[tid - off] : 0;
        __syncthreads();
        sh[tid] += t;
        __syncthreads();
    }
    if (tid < nbk) g->gbase[tid] = sh[tid] - v;
}

__global__ __launch_bounds__(256) void kB(GP a, GP b, int nb_a, int nb_b, int N, int Etot){
    int bid = blockIdx.x; const GP* g; int k;
    if (bid < nb_a){ g = &a; k = bid; }
    else { k = bid - nb_a; if (k >= nb_b) return; g = &b; }
    fine_dev(k, g, N, Etot);
}

// aggmix: n1 blocks of agg1 (graph g1) Bresenham-interleaved with n2 blocks of
// agg2 (graph g2). Used 3x: (AB1,0), (AB1,AB2) cross-graph, (0,AB2).
__global__ __launch_bounds__(BLK) void aggmix_k(
    GP g1, GP g2, const float* __restrict__ b1, const float* __restrict__ b2,
    const unsigned short* __restrict__ w2h, const unsigned short* __restrict__ w2l,
    const float* __restrict__ avs2, const float* __restrict__ avd2,
    int n1, int n2, int N)
{
    __shared__ unsigned short xlds[16 * 128];   // 4KB (agg1 role only)
    int bid = blockIdx.x;
    int T = n1 + n2;
    long lo  = (long)bid * n1 / T;
    long hi2 = (long)(bid + 1) * n1 / T;
    if (hi2 > lo){
        agg1_dev((int)lo, &g1, b1, w2h, w2l, avs2, avd2, N, xlds);
    } else {
        int l = bid - (int)lo;
        if (l < n2) agg2_dev(l, &g2, b2, N);
    }
}

// ---------------- host ----------------
extern "C" void kernel_launch(void* const* d_in, const int* in_sizes, int n_in,
                              void* d_out, int out_size, void* d_ws, size_t ws_size,
                              hipStream_t stream)
{
    const float* fea  = (const float*)d_in[0];
    const int*   ei   = (const int*)  d_in[1];
    const float* W1   = (const float*)d_in[2];
    const float* av_s1= (const float*)d_in[3];
    const float* av_d1= (const float*)d_in[4];
    const float* b1   = (const float*)d_in[5];
    const float* W2   = (const float*)d_in[6];
    const float* av_s2= (const float*)d_in[7];
    const float* av_d2= (const float*)d_in[8];
    const float* b2   = (const float*)d_in[9];
    float* out = (float*)d_out;

    const int B = 2;
    const int N = out_size / (B * 64);          // 50000 (pack requires N <= 65536)
    const int E = in_sizes[1] / (2 * B);        // 800000
    const int Etot = E + N;
    const int nbk = (N + 255) >> 8;             // 196 coarse buckets (<=256)

    size_t pg = 256 + (size_t)nbk * CAP + (size_t)(N + 2) + (size_t)Etot
              + (size_t)N * (64 + 32);
    size_t wtf = 8192 + 8192 + 4096 + 4096;
    auto total_f = [&](int ng){ return wtf + (size_t)ng * (4 * (size_t)N + 256) + (size_t)ng * pg + 64; };
    bool fused = (ws_size >= total_f(2) * sizeof(float));
    int NG = fused ? 2 : 1;

    float* ws = (float*)d_ws;
    size_t off = 0;
    unsigned short* w1h = (unsigned short*)(ws + off); off += 8192;
    unsigned short* w1l = (unsigned short*)(ws + off); off += 8192;
    unsigned short* w2h = (unsigned short*)(ws + off); off += 4096;
    unsigned short* w2l = (unsigned short*)(ws + off); off += 4096;

    float* zbase = ws + off;
    size_t znum = (size_t)NG * (4 * (size_t)N + 256);
    off += znum;

    GP g[2];
    for (int gi = 0; gi < NG; gi++){
        GP p;
        p.as1  = zbase + (size_t)gi * (4 * (size_t)N + 256);
        p.ad1  = p.as1 + N;
        p.as2  = p.ad1 + N;
        p.ad2  = p.as2 + N;
        p.gcnt = (int*)(p.ad2 + N);
        p.gbase  = (int*)(ws + off); off += 256;
        p.ebuf   = (int*)(ws + off); off += (size_t)nbk * CAP;
        p.rowptr = (int*)(ws + off); off += (size_t)(N + 2);
        p.csrsrc = (int*)(ws + off); off += Etot;
        p.h1b  = (unsigned short*)(ws + off); off += (size_t)N * 64;
        p.h2b  = (unsigned short*)(ws + off); off += (size_t)N * 32;
        g[gi] = p;
    }

    const int RT  = N >> 4;
    const int GB1 = cdiv(RT, 8) * 2;            // 2 row-tiles per wave -> 8 tiles/block
    const int EBk = cdiv(Etot, EPB);
    const int AB1 = cdiv(N, 16);                // agg1: 16 nodes/block
    const int AB2 = cdiv(N, 32);                // agg2: 32 nodes/block

    if (fused){
        for (int bi = 0; bi < 2; bi++){
            g[bi].src = ei + (size_t)bi * 2 * E;
            g[bi].dst = g[bi].src + E;
            g[bi].X   = fea + (size_t)bi * N * 128;
            g[bi].outp= out + (size_t)bi * N * 64;
        }
        hipMemsetAsync(zbase, 0, znum * sizeof(float), stream);
        prep_k<<<cdiv(128*128, BLK), BLK, 0, stream>>>(W1, W2, w1h, w1l, w2h, w2l);
        kA<<<2*EBk + 2*GB1, 256, 0, stream>>>(g[0], g[1], w1h, w1l, av_s1, av_d1,
                                              EBk, EBk, GB1, GB1, E, Etot, N, nbk);
        kscan<<<2, 256, 0, stream>>>(g[0], g[1], nbk);
        kB<<<2*nbk, 256, 0, stream>>>(g[0], g[1], nbk, nbk, N, Etot);
        // 3-stage cross-graph pipeline: agg1(g0) | agg1(g1)+agg2(g0) | agg2(g1)
        aggmix_k<<<AB1,       BLK, 0, stream>>>(g[0], g[0], b1, b2, w2h, w2l, av_s2, av_d2, AB1, 0,   N);
        aggmix_k<<<AB1 + AB2, BLK, 0, stream>>>(g[1], g[0], b1, b2, w2h, w2l, av_s2, av_d2, AB1, AB2, N);
        aggmix_k<<<AB2,       BLK, 0, stream>>>(g[1], g[1], b1, b2, w2h, w2l, av_s2, av_d2, 0,   AB2, N);
    } else {
        prep_k<<<cdiv(128*128, BLK), BLK, 0, stream>>>(W1, W2, w1h, w1l, w2h, w2l);
        for (int bi = 0; bi < B; bi++){
            GP p = g[0];
            p.src = ei + (size_t)bi * 2 * E;
            p.dst = p.src + E;
            p.X   = fea + (size_t)bi * N * 128;
            p.outp= out + (size_t)bi * N * 64;
            hipMemsetAsync(zbase, 0, znum * sizeof(float), stream);
            kA<<<EBk + GB1, 256, 0, stream>>>(p, p, w1h, w1l, av_s1, av_d1,
                                              EBk, 0, GB1, 0, E, Etot, N, nbk);
            kscan<<<1, 256, 0, stream>>>(p, p, nbk);
            kB<<<nbk, 256, 0, stream>>>(p, p, nbk, 0, N, Etot);
            aggmix_k<<<AB1, BLK, 0, stream>>>(p, p, b1, b2, w2h, w2l, av_s2, av_d2, AB1, 0, N);
            aggmix_k<<<AB2, BLK, 0, stream>>>(p, p, b1, b2, w2h, w2l, av_s2, av_d2, 0, AB2, N);
        }
    }
}

// Round 19
// 200.527 us; speedup vs baseline: 1.1307x; 1.1307x over previous
//
#include <hip/hip_runtime.h>

#define NEG_SLOPE 0.2f
static constexpr int BLK = 256;
static constexpr int EPB = 4096;   // edges per bucket-pass block
static constexpr int CAP = 6144;   // per-bucket capacity (mean 4336, +27 sigma)

typedef short bf16x8 __attribute__((ext_vector_type(8)));
typedef float f32x4  __attribute__((ext_vector_type(4)));
typedef unsigned short u16x8 __attribute__((ext_vector_type(8)));
typedef unsigned short u16x4 __attribute__((ext_vector_type(4)));

static inline int cdiv(long a, long b){ return (int)((a + b - 1) / b); }

__device__ __forceinline__ unsigned short f2bf(float f){
    unsigned u = __float_as_uint(f);
    u += 0x7fff + ((u >> 16) & 1);          // RNE
    return (unsigned short)(u >> 16);
}
__device__ __forceinline__ float bf2f(unsigned short h){
    return __uint_as_float(((unsigned)h) << 16);
}
__device__ __forceinline__ float lrelu(float v){
    return v > 0.f ? v : NEG_SLOPE * v;
}

// ---------------- per-graph pointer bundle ----------------
struct GP {
    const int* src; const int* dst; const float* X;
    int* gcnt; int* gbase; int* ebuf; int* rowptr; int* csrsrc;
    unsigned short* h1b; unsigned short* h2b;
    float *as1, *ad1, *as2, *ad2; float* outp;
};

// ---------------- LDS-staged MFMA GEMM: h = W_split x bf16(x) ----------------
// Block = 8 row-tiles (128 rows) x one col-chunk; each wave owns TWO row-tiles.
template<int CO, int CT, bool RELU_IN, bool BF16OUT>
__device__ __forceinline__ void gemm_dev(
    int bid, const float* __restrict__ X,
    const unsigned short* __restrict__ Wt_hi, const unsigned short* __restrict__ Wt_lo,
    const float* __restrict__ avs, const float* __restrict__ avd,
    void* __restrict__ Hout, float* __restrict__ as_out, float* __restrict__ ad_out,
    int N, unsigned short* smem)
{
    constexpr int CHUNKS = CO / (CT * 16);
    constexpr int HWB = CT * 4096;
    int ch, rtb;
    if (CHUNKS == 1){ ch = 0; rtb = bid; } else { ch = bid & 1; rtb = bid >> 1; }
    int c0 = ch * (CT * 16);

    {
        const char* srch = (const char*)(Wt_hi + (size_t)c0 * 128);
        const char* srcl = (const char*)(Wt_lo + (size_t)c0 * 128);
        #pragma unroll
        for (int it = 0; it < CT * 2; ++it){
            int o = (it * 256 + (int)threadIdx.x) * 16;
            const char* sp = (o < HWB) ? (srch + o) : (srcl + (o - HWB));
            u16x8 v = *(const u16x8*)sp;
            int so = o ^ (((o >> 8) & 7) << 4);
            *(u16x8*)((char*)smem + so) = v;
        }
    }
    __syncthreads();

    int wave = threadIdx.x >> 6;
    int lane = threadIdx.x & 63;
    int RTt = N >> 4;
    int rt0 = rtb * 8 + wave;
    int rt1 = rt0 + 4;
    if (rt0 >= RTt) return;
    bool vB = rt1 < RTt;
    int rl = lane & 15, g = lane >> 4;
    const float* xrowA = X + (long)(rt0 * 16 + rl) * 128 + g * 8;
    const float* xrowB = X + (long)((vB ? rt1 : rt0) * 16 + rl) * 128 + g * 8;

    f32x4 accA[CT], accB[CT];
    #pragma unroll
    for (int t = 0; t < CT; t++){ accA[t] = (f32x4)(0.f); accB[t] = (f32x4)(0.f); }

    int sw = (rl & 7) << 4;
    #pragma unroll
    for (int ks = 0; ks < 4; ks++){
        float4 xaA = *(const float4*)(xrowA + ks * 32);
        float4 xbA = *(const float4*)(xrowA + ks * 32 + 4);
        float4 xaB = *(const float4*)(xrowB + ks * 32);
        float4 xbB = *(const float4*)(xrowB + ks * 32 + 4);
        float xvA[8] = {xaA.x, xaA.y, xaA.z, xaA.w, xbA.x, xbA.y, xbA.z, xbA.w};
        float xvB[8] = {xaB.x, xaB.y, xaB.z, xaB.w, xbB.x, xbB.y, xbB.z, xbB.w};
        bf16x8 xbfA, xbfB;
        #pragma unroll
        for (int j = 0; j < 8; j++){
            float xA = xvA[j], xB = xvB[j];
            if (RELU_IN){ xA = fmaxf(xA, 0.f); xB = fmaxf(xB, 0.f); }
            xbfA[j] = (short)f2bf(xA);
            xbfB[j] = (short)f2bf(xB);
        }
        int rbase = rl * 256 + ks * 64 + g * 16;
        #pragma unroll
        for (int t = 0; t < CT; t++){
            bf16x8 wh = *(const bf16x8*)((char*)smem + ((t * 4096 + rbase) ^ sw));
            bf16x8 wl = *(const bf16x8*)((char*)smem + ((HWB + t * 4096 + rbase) ^ sw));
            accA[t] = __builtin_amdgcn_mfma_f32_16x16x32_bf16(wh, xbfA, accA[t], 0, 0, 0);
            accB[t] = __builtin_amdgcn_mfma_f32_16x16x32_bf16(wh, xbfB, accB[t], 0, 0, 0);
            accA[t] = __builtin_amdgcn_mfma_f32_16x16x32_bf16(wl, xbfA, accA[t], 0, 0, 0);
            accB[t] = __builtin_amdgcn_mfma_f32_16x16x32_bf16(wl, xbfB, accB[t], 0, 0, 0);
        }
    }

    #pragma unroll
    for (int half = 0; half < 2; half++){
        if (half == 1 && !vB) break;
        int r0 = (half == 0 ? rt0 : rt1) << 4;
        f32x4* acc = (half == 0) ? accA : accB;
        float ps = 0.f, pd = 0.f;
        #pragma unroll
        for (int t = 0; t < CT; t++){
            int c = c0 + t * 16 + 4 * g;
            float4 vs4 = *(const float4*)(avs + c);
            float4 vd4 = *(const float4*)(avd + c);
            ps += acc[t][0]*vs4.x + acc[t][1]*vs4.y + acc[t][2]*vs4.z + acc[t][3]*vs4.w;
            pd += acc[t][0]*vd4.x + acc[t][1]*vd4.y + acc[t][2]*vd4.z + acc[t][3]*vd4.w;
            long base = (long)(r0 + rl) * CO + c;
            if (BF16OUT){
                u16x4 pk;
                #pragma unroll
                for (int r = 0; r < 4; r++) pk[r] = f2bf(acc[t][r]);
                *(u16x4*)((unsigned short*)Hout + base) = pk;
            } else {
                float4 pv;
                pv.x = acc[t][0]; pv.y = acc[t][1]; pv.z = acc[t][2]; pv.w = acc[t][3];
                *(float4*)((float*)Hout + base) = pv;
            }
        }
        ps += __shfl_xor(ps, 16, 64); ps += __shfl_xor(ps, 32, 64);
        pd += __shfl_xor(pd, 16, 64); pd += __shfl_xor(pd, 32, 64);
        if (g == 0){
            unsafeAtomicAdd(as_out + r0 + rl, ps);
            unsafeAtomicAdd(ad_out + r0 + rl, pd);
        }
    }
}

// ---------------- coarse bucket pass (LDS histogram + reserved scatter) ----------------
__device__ __forceinline__ void bucket_dev(
    int bid, const GP* __restrict__ g, int E, int Etot, int nbk, unsigned short* smem)
{
    int* spk   = (int*)smem;          // 4096 ints
    int* shist = spk + 4096;          // 256
    int* sbase = shist + 256;         // 256
    int tid = (int)threadIdx.x;
    for (int i = tid; i < nbk; i += 256) shist[i] = 0;
    __syncthreads();
    int e0 = bid * EPB;
    #pragma unroll
    for (int i = 0; i < EPB / 256; i++){
        int idx = i * 256 + tid; int e = e0 + idx;
        unsigned p = 0xFFFFFFFFu;
        if (e < Etot){
            int s, d;
            if (e < E){ s = g->src[e]; d = g->dst[e]; } else { s = e - E; d = s; }
            p = ((unsigned)s << 16) | (unsigned)d;
            atomicAdd(&shist[d >> 8], 1);
        }
        spk[idx] = (int)p;
    }
    __syncthreads();
    for (int i = tid; i < nbk; i += 256){
        sbase[i] = atomicAdd(&g->gcnt[i], shist[i]);
        shist[i] = 0;                 // reuse as fill counter
    }
    __syncthreads();
    #pragma unroll
    for (int i = 0; i < EPB / 256; i++){
        int idx = i * 256 + tid;
        unsigned p = (unsigned)spk[idx];
        if (p != 0xFFFFFFFFu){
            int d = (int)(p & 0xFFFFu); int b = d >> 8;
            int r = sbase[b] + atomicAdd(&shist[b], 1);
            if (r < CAP) g->ebuf[(size_t)b * CAP + r] = (int)p;
        }
    }
}

// ---------------- fine pass: per-bucket CSR (rowptr + sorted csrsrc) ----------------
__device__ __forceinline__ void fine_dev(int k, const GP* __restrict__ g, int N, int Etot)
{
    __shared__ int pk2[CAP];
    __shared__ int fs[256];
    __shared__ int fill[256];
    __shared__ int fh[256];
    int tid = (int)threadIdx.x;
    int cnt = min(g->gcnt[k], CAP);
    int bb  = g->gbase[k];
    for (int i = tid; i < cnt; i += 256) pk2[i] = g->ebuf[(size_t)k * CAP + i];
    fh[tid] = 0; fill[tid] = 0;
    __syncthreads();
    for (int i = tid; i < cnt; i += 256) atomicAdd(&fh[pk2[i] & 255], 1);
    __syncthreads();
    int v = fh[tid];
    fs[tid] = v;
    __syncthreads();
    #pragma unroll
    for (int off = 1; off < 256; off <<= 1){
        int t = (tid >= off) ? fs[tid - off] : 0;
        __syncthreads();
        fs[tid] += t;
        __syncthreads();
    }
    int excl = fs[tid] - v;
    __syncthreads();
    fs[tid] = excl;
    __syncthreads();
    int node = k * 256 + tid;
    if (node < N) g->rowptr[node] = bb + excl;
    if (k == 0 && tid == 0) g->rowptr[N] = Etot;
    for (int i = tid; i < cnt; i += 256){
        unsigned p = (unsigned)pk2[i];
        int f = (int)(p & 255u);
        int r = atomicAdd(&fill[f], 1);
        g->csrsrc[bb + fs[f] + r] = (int)(p >> 16);
    }
}

// ---------------- gather core: softmax + weighted row accumulation ----------------
template<int CO, int GRP>
__device__ __forceinline__ void agg_core(
    const int* __restrict__ rowptr, const int* __restrict__ csr_src,
    const float* __restrict__ as, const float* __restrict__ ad,
    const unsigned short* __restrict__ hb, int node, int ql, float* acc)
{
    int start = rowptr[node];
    int deg   = rowptr[node + 1] - start;
    float adv = ad[node];

    int sv[4]; float ev[4];
    #pragma unroll
    for (int q = 0; q < 4; q++){
        int idx = q * GRP + ql;
        sv[q] = 0; ev[q] = -1e30f;
        if (idx < deg){ sv[q] = csr_src[start + idx]; ev[q] = lrelu(as[sv[q]] + adv); }
    }
    float m = fmaxf(fmaxf(ev[0], ev[1]), fmaxf(ev[2], ev[3]));
    if (deg > 4 * GRP){
        for (int j = 4 * GRP + ql; j < deg; j += GRP)
            m = fmaxf(m, lrelu(as[csr_src[start + j]] + adv));
    }
    #pragma unroll
    for (int off = GRP >> 1; off; off >>= 1) m = fmaxf(m, __shfl_xor(m, off, GRP));

    float xq[4]; float sum = 0.f;
    #pragma unroll
    for (int q = 0; q < 4; q++){
        xq[q] = (q * GRP + ql < deg) ? __expf(ev[q] - m) : 0.f;
        sum += xq[q];
    }
    if (deg > 4 * GRP){
        for (int j = 4 * GRP + ql; j < deg; j += GRP)
            sum += __expf(lrelu(as[csr_src[start + j]] + adv) - m);
    }
    #pragma unroll
    for (int off = GRP >> 1; off; off >>= 1) sum += __shfl_xor(sum, off, GRP);
    float inv = 1.f / (sum + 1e-16f);

    #pragma unroll
    for (int i = 0; i < 8; i++) acc[i] = 0.f;

    #pragma unroll
    for (int q = 0; q < 4; q++){
        int rem = deg - q * GRP;
        if (rem <= 0) break;
        int lim = rem < GRP ? rem : GRP;
        float aq = xq[q] * inv; int sq = sv[q];
        int t = 0;
        for (; t + 3 < lim; t += 4){
            int   s0 = __shfl(sq, t+0, GRP), s1 = __shfl(sq, t+1, GRP);
            int   s2 = __shfl(sq, t+2, GRP), s3 = __shfl(sq, t+3, GRP);
            float a0 = __shfl(aq, t+0, GRP), a1 = __shfl(aq, t+1, GRP);
            float a2 = __shfl(aq, t+2, GRP), a3 = __shfl(aq, t+3, GRP);
            u16x8 r0 = *(const u16x8*)(hb + (long)s0 * CO + ql * 8);
            u16x8 r1 = *(const u16x8*)(hb + (long)s1 * CO + ql * 8);
            u16x8 r2 = *(const u16x8*)(hb + (long)s2 * CO + ql * 8);
            u16x8 r3 = *(const u16x8*)(hb + (long)s3 * CO + ql * 8);
            #pragma unroll
            for (int i = 0; i < 8; i++)
                acc[i] += a0 * bf2f(r0[i]) + a1 * bf2f(r1[i])
                        + a2 * bf2f(r2[i]) + a3 * bf2f(r3[i]);
        }
        for (; t < lim; t++){
            int   s0 = __shfl(sq, t, GRP);
            float a0 = __shfl(aq, t, GRP);
            u16x8 r0 = *(const u16x8*)(hb + (long)s0 * CO + ql * 8);
            #pragma unroll
            for (int i = 0; i < 8; i++) acc[i] += a0 * bf2f(r0[i]);
        }
        if (lim < GRP) break;
    }
    if (deg > 4 * GRP){
        for (int j = 4 * GRP; j < deg; j++){
            int sj = csr_src[start + j];               // group-uniform broadcast load
            float aj = __expf(lrelu(as[sj] + adv) - m) * inv;
            u16x8 r0 = *(const u16x8*)(hb + (long)sj * CO + ql * 8);
            #pragma unroll
            for (int i = 0; i < 8; i++) acc[i] += aj * bf2f(r0[i]);
        }
    }
}

// ---------------- kernels ----------------
__global__ __launch_bounds__(BLK) void prep_k(
    const float* __restrict__ W1, const float* __restrict__ W2,
    unsigned short* __restrict__ w1h, unsigned short* __restrict__ w1l,
    unsigned short* __restrict__ w2h, unsigned short* __restrict__ w2l)
{
    int i = blockIdx.x * BLK + threadIdx.x;
    if (i < 128 * 128){
        int c = i >> 7, k = i & 127;
        float w = W1[k * 128 + c];
        unsigned short hi = f2bf(w);
        w1h[i] = hi; w1l[i] = f2bf(w - bf2f(hi));
        if (i < 64 * 128){
            float w2 = W2[k * 64 + c];
            unsigned short hi2 = f2bf(w2);
            w2h[i] = hi2; w2l[i] = f2bf(w2 - bf2f(hi2));
        }
    }
}

// kA: coarse bucket pass (both graphs) + layer-1 GEMM (both graphs)
__global__ __launch_bounds__(256, 4) void kA(
    GP a, GP b, const unsigned short* __restrict__ w1h, const unsigned short* __restrict__ w1l,
    const float* __restrict__ avs1, const float* __restrict__ avd1,
    int EB_a, int EB_b, int GB_a, int GB_b, int E, int Etot, int N, int nbk)
{
    __shared__ unsigned short smem[16384];
    int bid = blockIdx.x;
    if (bid < EB_a){ bucket_dev(bid, &a, E, Etot, nbk, smem); return; }
    bid -= EB_a;
    if (bid < EB_b){ bucket_dev(bid, &b, E, Etot, nbk, smem); return; }
    bid -= EB_b;
    if (bid < GB_a){ gemm_dev<128,4,false,true>(bid, a.X, w1h, w1l, avs1, avd1, a.h1b, a.as1, a.ad1, N, smem); return; }
    bid -= GB_a;
    if (bid < GB_b) gemm_dev<128,4,false,true>(bid, b.X, w1h, w1l, avs1, avd1, b.h1b, b.as1, b.ad1, N, smem);
}

__global__ __launch_bounds__(256) void kscan(GP a, GP b, int nbk){
    const GP* g = (blockIdx.x == 0) ? &a : &b;
    __shared__ int sh[256];
    int tid = (int)threadIdx.x;
    int v = (tid < nbk) ? g->gcnt[tid] : 0;
    sh[tid] = v;
    __syncthreads();
    #pragma unroll
    for (int off = 1; off < 256; off <<= 1){
        int t = (tid >= off) ? sh[tid - off] : 0;
        __syncthreads();
        sh[tid] += t;
        __syncthreads();
    }
    if (tid < nbk) g->gbase[tid] = sh[tid] - v;
}

__global__ __launch_bounds__(256) void kB(GP a, GP b, int nb_a, int nb_b, int N, int Etot){
    int bid = blockIdx.x; const GP* g; int k;
    if (bid < nb_a){ g = &a; k = bid; }
    else { k = bid - nb_a; if (k >= nb_b) return; g = &b; }
    fine_dev(k, g, N, Etot);
}

// agg1f: layer-1 aggregation (16-lane groups, 16 nodes/block) + FUSED layer-2 GEMM.
// R15's proven form: one gather phase, one barrier, 1-tile MFMA epilogue per wave.
__global__ __launch_bounds__(BLK) void agg1f_k(
    GP a, GP b, const float* __restrict__ b1,
    const unsigned short* __restrict__ w2h, const unsigned short* __restrict__ w2l,
    const float* __restrict__ avs2, const float* __restrict__ avd2,
    int AB_a, int AB_b, int N)
{
    __shared__ unsigned short xlds[16 * 128];   // 4KB bf16 x-tile
    int bid = blockIdx.x; const GP* g;
    if (bid < AB_a){ g = &a; }
    else { bid -= AB_a; if (bid >= AB_b) return; g = &b; }
    int tid = (int)threadIdx.x;
    int grp = tid >> 4, ql = tid & 15;
    int node = bid * 16 + grp;

    {
        u16x8 xv;
        if (node < N){
            float acc[8];
            agg_core<128,16>(g->rowptr, g->csrsrc, g->as1, g->ad1, g->h1b, node, ql, acc);
            #pragma unroll
            for (int i = 0; i < 8; i++)
                xv[i] = f2bf(fmaxf(acc[i] + b1[ql * 8 + i], 0.f));
        } else {
            #pragma unroll
            for (int i = 0; i < 8; i++) xv[i] = 0;
        }
        int bo = (grp * 256 + ql * 16) ^ ((grp & 7) << 4);
        *(u16x8*)((char*)xlds + bo) = xv;
    }
    __syncthreads();

    // MFMA phase: wave wv -> cols wv*16..+15 of all 16 nodes
    int lane = tid & 63, wv = tid >> 6;
    int rl = lane & 15, kg = lane >> 4;
    f32x4 d = (f32x4)(0.f);
    #pragma unroll
    for (int kb = 0; kb < 4; kb++){
        bf16x8 af = *(const bf16x8*)((char*)xlds + ((rl * 256 + kb * 64 + kg * 16) ^ ((rl & 7) << 4)));
        long wo = (long)(wv * 16 + rl) * 128 + kb * 32 + kg * 8;
        bf16x8 bh = *(const bf16x8*)(w2h + wo);
        bf16x8 bl = *(const bf16x8*)(w2l + wo);
        d = __builtin_amdgcn_mfma_f32_16x16x32_bf16(af, bh, d, 0, 0, 0);
        d = __builtin_amdgcn_mfma_f32_16x16x32_bf16(af, bl, d, 0, 0, 0);
    }
    // D mapping: lane holds D[row=4*kg+reg][col=rl]
    float pvs = avs2[wv * 16 + rl], pvd = avd2[wv * 16 + rl];
    #pragma unroll
    for (int reg = 0; reg < 4; reg++){
        int nd = bid * 16 + 4 * kg + reg;
        float hv = d[reg];
        if (nd < N) g->h2b[(long)nd * 64 + wv * 16 + rl] = f2bf(hv);
        float s_ = hv * pvs, d_ = hv * pvd;
        #pragma unroll
        for (int off = 1; off < 16; off <<= 1){
            s_ += __shfl_xor(s_, off, 16);
            d_ += __shfl_xor(d_, off, 16);
        }
        if (rl == 0 && nd < N){
            unsafeAtomicAdd(g->as2 + nd, s_);
            unsafeAtomicAdd(g->ad2 + nd, d_);
        }
    }
}

// agg2f: final-layer aggregation (8-lane groups, 32 nodes/block) + bias, f32 out
__global__ __launch_bounds__(BLK) void agg2f_k(
    GP a, GP b, const float* __restrict__ bias, int AB_a, int AB_b, int N)
{
    int bid = blockIdx.x; const GP* g;
    if (bid < AB_a){ g = &a; }
    else { bid -= AB_a; if (bid >= AB_b) return; g = &b; }
    int tid = (int)threadIdx.x;
    int grp = tid >> 3, ql = tid & 7;
    int node = bid * 32 + grp;
    if (node >= N) return;
    float acc[8];
    agg_core<64,8>(g->rowptr, g->csrsrc, g->as2, g->ad2, g->h2b, node, ql, acc);
    float* o = g->outp + (long)node * 64 + ql * 8;
    #pragma unroll
    for (int i = 0; i < 8; i += 4){
        float4 ov;
        ov.x = acc[i+0] + bias[ql * 8 + i + 0];
        ov.y = acc[i+1] + bias[ql * 8 + i + 1];
        ov.z = acc[i+2] + bias[ql * 8 + i + 2];
        ov.w = acc[i+3] + bias[ql * 8 + i + 3];
        *(float4*)(o + i) = ov;
    }
}

// ---------------- host ----------------
extern "C" void kernel_launch(void* const* d_in, const int* in_sizes, int n_in,
                              void* d_out, int out_size, void* d_ws, size_t ws_size,
                              hipStream_t stream)
{
    const float* fea  = (const float*)d_in[0];
    const int*   ei   = (const int*)  d_in[1];
    const float* W1   = (const float*)d_in[2];
    const float* av_s1= (const float*)d_in[3];
    const float* av_d1= (const float*)d_in[4];
    const float* b1   = (const float*)d_in[5];
    const float* W2   = (const float*)d_in[6];
    const float* av_s2= (const float*)d_in[7];
    const float* av_d2= (const float*)d_in[8];
    const float* b2   = (const float*)d_in[9];
    float* out = (float*)d_out;

    const int B = 2;
    const int N = out_size / (B * 64);          // 50000 (pack requires N <= 65536)
    const int E = in_sizes[1] / (2 * B);        // 800000
    const int Etot = E + N;
    const int nbk = (N + 255) >> 8;             // 196 coarse buckets (<=256)

    size_t pg = 256 + (size_t)nbk * CAP + (size_t)(N + 2) + (size_t)Etot
              + (size_t)N * (64 + 32);
    size_t wtf = 8192 + 8192 + 4096 + 4096;
    auto total_f = [&](int ng){ return wtf + (size_t)ng * (4 * (size_t)N + 256) + (size_t)ng * pg + 64; };
    bool fused = (ws_size >= total_f(2) * sizeof(float));
    int NG = fused ? 2 : 1;

    float* ws = (float*)d_ws;
    size_t off = 0;
    unsigned short* w1h = (unsigned short*)(ws + off); off += 8192;
    unsigned short* w1l = (unsigned short*)(ws + off); off += 8192;
    unsigned short* w2h = (unsigned short*)(ws + off); off += 4096;
    unsigned short* w2l = (unsigned short*)(ws + off); off += 4096;

    float* zbase = ws + off;
    size_t znum = (size_t)NG * (4 * (size_t)N + 256);
    off += znum;

    GP g[2];
    for (int gi = 0; gi < NG; gi++){
        GP p;
        p.as1  = zbase + (size_t)gi * (4 * (size_t)N + 256);
        p.ad1  = p.as1 + N;
        p.as2  = p.ad1 + N;
        p.ad2  = p.as2 + N;
        p.gcnt = (int*)(p.ad2 + N);
        p.gbase  = (int*)(ws + off); off += 256;
        p.ebuf   = (int*)(ws + off); off += (size_t)nbk * CAP;
        p.rowptr = (int*)(ws + off); off += (size_t)(N + 2);
        p.csrsrc = (int*)(ws + off); off += Etot;
        p.h1b  = (unsigned short*)(ws + off); off += (size_t)N * 64;
        p.h2b  = (unsigned short*)(ws + off); off += (size_t)N * 32;
        g[gi] = p;
    }

    const int RT  = N >> 4;
    const int GB1 = cdiv(RT, 8) * 2;            // 2 row-tiles per wave -> 8 tiles/block
    const int EBk = cdiv(Etot, EPB);
    const int AB1 = cdiv(N, 16);                // agg1f: 16 nodes/block
    const int AB2 = cdiv(N, 32);                // agg2f: 32 nodes/block

    if (fused){
        for (int bi = 0; bi < 2; bi++){
            g[bi].src = ei + (size_t)bi * 2 * E;
            g[bi].dst = g[bi].src + E;
            g[bi].X   = fea + (size_t)bi * N * 128;
            g[bi].outp= out + (size_t)bi * N * 64;
        }
        hipMemsetAsync(zbase, 0, znum * sizeof(float), stream);
        prep_k<<<cdiv(128*128, BLK), BLK, 0, stream>>>(W1, W2, w1h, w1l, w2h, w2l);
        kA<<<2*EBk + 2*GB1, 256, 0, stream>>>(g[0], g[1], w1h, w1l, av_s1, av_d1,
                                              EBk, EBk, GB1, GB1, E, Etot, N, nbk);
        kscan<<<2, 256, 0, stream>>>(g[0], g[1], nbk);
        kB<<<2*nbk, 256, 0, stream>>>(g[0], g[1], nbk, nbk, N, Etot);
        agg1f_k<<<2*AB1, BLK, 0, stream>>>(g[0], g[1], b1, w2h, w2l, av_s2, av_d2, AB1, AB1, N);
        agg2f_k<<<2*AB2, BLK, 0, stream>>>(g[0], g[1], b2, AB2, AB2, N);
    } else {
        prep_k<<<cdiv(128*128, BLK), BLK, 0, stream>>>(W1, W2, w1h, w1l, w2h, w2l);
        for (int bi = 0; bi < B; bi++){
            GP p = g[0];
            p.src = ei + (size_t)bi * 2 * E;
            p.dst = p.src + E;
            p.X   = fea + (size_t)bi * N * 128;
            p.outp= out + (size_t)bi * N * 64;
            hipMemsetAsync(zbase, 0, znum * sizeof(float), stream);
            kA<<<EBk + GB1, 256, 0, stream>>>(p, p, w1h, w1l, av_s1, av_d1,
                                              EBk, 0, GB1, 0, E, Etot, N, nbk);
            kscan<<<1, 256, 0, stream>>>(p, p, nbk);
            kB<<<nbk, 256, 0, stream>>>(p, p, nbk, 0, N, Etot);
            agg1f_k<<<AB1, BLK, 0, stream>>>(p, p, b1, w2h, w2l, av_s2, av_d2, AB1, 0, N);
            agg2f_k<<<AB2, BLK, 0, stream>>>(p, p, b2, AB2, 0, N);
        }
    }
}